// Round 7
// baseline (1644.613 us; speedup 1.0000x reference)
//
#include <hip/hip_runtime.h>

#define SEQ   1024
#define BATCH 512
#define HID   128
#define GC    512   // 4 gates * HID

typedef __attribute__((ext_vector_type(8))) short          short8v;
typedef __attribute__((ext_vector_type(4))) float          float4v;
typedef __attribute__((ext_vector_type(2))) float          float2v;
typedef __attribute__((ext_vector_type(4))) unsigned short ushort4v;
typedef __attribute__((ext_vector_type(8))) unsigned short ushort8v;

__device__ __forceinline__ unsigned short f2bf(float f) {
    union { float f; unsigned u; } v; v.f = f;
    return (unsigned short)((v.u + 0x7fffu + ((v.u >> 16) & 1u)) >> 16);
}
__device__ __forceinline__ float bf2f(unsigned short u) {
    union { unsigned u; float f; } v; v.u = ((unsigned)u) << 16;
    return v.f;
}
__device__ __forceinline__ float fast_cos(float x) {
    return __builtin_amdgcn_cosf(x * 0.15915494309189535f);   // v_cos takes revolutions
}
__device__ __forceinline__ float fast_sigmoid(float x) {
    return __builtin_amdgcn_rcpf(1.0f + __builtin_amdgcn_exp2f(-1.4426950408889634f * x));
}
__device__ __forceinline__ float fast_tanh(float x) {
    return 1.0f - 2.0f * __builtin_amdgcn_rcpf(1.0f + __builtin_amdgcn_exp2f(2.8853900817779268f * x));
}

// DPP helper: returns src shifted by CTRL, invalid/masked lanes get 1.0f
template<int CTRL, int RM>
__device__ __forceinline__ float dpp1(float v) {
    union { float f; int i; } s, o, r;
    s.f = v; o.f = 1.0f;
    r.i = __builtin_amdgcn_update_dpp(o.i, s.i, CTRL, RM, 0xf, false);
    return r.f;
}

// raw barrier: drains LDS only; global loads/stores stay in flight across it
#define BAR() do { asm volatile("s_waitcnt lgkmcnt(0)" ::: "memory");  \
                   __builtin_amdgcn_s_barrier();                       \
                   __builtin_amdgcn_sched_barrier(0); } while (0)

// ---------------------------------------------------------------------------
// Kernel 0: X f32 -> bf16 streaming convert (chunk slice)
// ---------------------------------------------------------------------------
__global__ __launch_bounds__(256) void xbf_kernel(
    const float* __restrict__ X, unsigned short* __restrict__ Xb, int n8)
{
    int i = blockIdx.x * 256 + threadIdx.x;
    const int stride = gridDim.x * 256;
    for (; i < n8; i += stride) {
        float4v a = *(const float4v*)(X + (size_t)i * 8);
        float4v b = *(const float4v*)(X + (size_t)i * 8 + 4);
        ushort8v o;
        #pragma unroll
        for (int j = 0; j < 4; ++j) { o[j] = f2bf(a[j]); o[4 + j] = f2bf(b[j]); }
        *(ushort8v*)(Xb + (size_t)i * 8) = o;
    }
}

// ---------------------------------------------------------------------------
// Kernel 1: Z[row][g*128+c] = bf16( Xb[row][:] @ Wg_x[:,c] + b ).  (unchanged)
// ---------------------------------------------------------------------------
__global__ __launch_bounds__(512, 4) void qlstm_xgemm(
    const unsigned short* __restrict__ Xb,   // [rows][128] bf16
    const float* __restrict__ Wf, const float* __restrict__ bfp,
    const float* __restrict__ Wi, const float* __restrict__ bip,
    const float* __restrict__ Wg, const float* __restrict__ bgp,
    const float* __restrict__ Wo, const float* __restrict__ bop,
    unsigned short* __restrict__ Z)
{
    const int tid = threadIdx.x, lane = tid & 63, wid = tid >> 6;
    const int l15 = lane & 15, kg = lane >> 4;
    const int g = wid >> 1;
    const float* Wsel = (g == 0) ? Wf : (g == 1) ? Wi : (g == 2) ? Wg : Wo;
    const float* bsel = (g == 0) ? bfp : (g == 1) ? bip : (g == 2) ? bgp : bop;
    const int cb  = (wid & 1) * 64;
    const int zcb = wid * 64;

    short8v aw[4][4];
    #pragma unroll
    for (int mt = 0; mt < 4; ++mt) {
        const int col = cb + mt * 16 + l15;
        #pragma unroll
        for (int ks = 0; ks < 4; ++ks) {
            const int k0 = ks * 32 + kg * 8;
            short8v a;
            #pragma unroll
            for (int j = 0; j < 8; ++j)
                a[j] = (short)f2bf(Wsel[(size_t)(k0 + j) * HID + col]);
            aw[mt][ks] = a;
        }
    }
    ushort4v biasb[4];
    #pragma unroll
    for (int mt = 0; mt < 4; ++mt)
        #pragma unroll
        for (int j = 0; j < 4; ++j)
            biasb[mt][j] = f2bf(bsel[cb + mt * 16 + kg * 4 + j]);

    const int rowbase = blockIdx.x * 128;

    short8v bx[4];
    {
        const unsigned short* xr = Xb + (size_t)(rowbase + l15) * HID;
        #pragma unroll
        for (int ks = 0; ks < 4; ++ks)
            bx[ks] = *(const short8v*)(xr + ks * 32 + kg * 8);
    }

    for (int rg = 0; rg < 8; ++rg) {
        float4v acc[4];
        #pragma unroll
        for (int mt = 0; mt < 4; ++mt)
            #pragma unroll
            for (int j = 0; j < 4; ++j) acc[mt][j] = bf2f(biasb[mt][j]);

        #pragma unroll
        for (int ks = 0; ks < 4; ++ks)
            #pragma unroll
            for (int mt = 0; mt < 4; ++mt)
                acc[mt] = __builtin_amdgcn_mfma_f32_16x16x32_bf16(aw[mt][ks], bx[ks], acc[mt], 0, 0, 0);

        if (rg < 7) {
            const unsigned short* xr = Xb + (size_t)(rowbase + (rg + 1) * 16 + l15) * HID;
            #pragma unroll
            for (int ks = 0; ks < 4; ++ks)
                bx[ks] = *(const short8v*)(xr + ks * 32 + kg * 8);
        }

        const size_t zr = (size_t)(rowbase + rg * 16 + l15) * GC + zcb;
        #pragma unroll
        for (int mt = 0; mt < 4; ++mt) {
            ushort4v o;
            #pragma unroll
            for (int j = 0; j < 4; ++j) o[j] = f2bf(acc[mt][j]);
            *(ushort4v*)&Z[zr + mt * 16 + kg * 4] = o;
        }
    }
}

// ---------------------------------------------------------------------------
// Kernel 2: recurrent. 512 WGs x 256 thr (4 waves), 1 batch row/WG, 2 WGs/CU.
// ONE barrier per step:
//   MFMA (wave g = gate g, A = h broadcast via 16 ds_bpermute from lane-local
//   h pairs, B = Wh frags in regs) -> in-wave activation of 2 own cols/lane
//   (static-index selects) -> publish to parity-buffered gact -> BAR ->
//   every wave REDUNDANTLY does DPP cumprod scan + cell update for cols
//   {2*lane, 2*lane+1}, h kept as lane-local bf16x2, c in f32 regs.
// gact parity double-buffer + lgkm-draining barrier => WAR race-free.
// ---------------------------------------------------------------------------
__global__ __launch_bounds__(256, 2) void qlstm_rec(
    const unsigned short* __restrict__ Z,   // [chunk][BATCH][GC] bf16
    const float* __restrict__ Wf, const float* __restrict__ Wi,
    const float* __restrict__ Wg, const float* __restrict__ Wo,
    float* __restrict__ out,
    unsigned short* __restrict__ hstate,    // bf16 [BATCH][HID]
    float* __restrict__ cstate,             // f32  [BATCH][HID]
    int t0, int chunk, int last)
{
    __shared__ float gact[2][4][HID];       // [parity][gate][col]; gate0 = cos(f)

    const int tid = threadIdx.x, lane = tid & 63, wid = tid >> 6;
    const int l15 = lane & 15, kg = lane >> 4;
    const int b = blockIdx.x;               // batch row
    const float* Wsel = (wid == 0) ? Wf : (wid == 1) ? Wi : (wid == 2) ? Wg : Wo;

    // B-frags: bw[n][ks] = W[128 + ks*32 + kg*8 + j][n*16 + l15]   (128 VGPR)
    short8v bw[8][4];
    #pragma unroll
    for (int n = 0; n < 8; ++n) {
        const int col = n * 16 + l15;
        #pragma unroll
        for (int ks = 0; ks < 4; ++ks) {
            const int k0 = 128 + ks * 32 + kg * 8;
            short8v a;
            #pragma unroll
            for (int j = 0; j < 8; ++j)
                a[j] = (short)f2bf(Wsel[(size_t)(k0 + j) * HID + col]);
            bw[n][ks] = a;
        }
    }

    // lane-local state: cell cols {2*lane, 2*lane+1} (all 4 waves redundant)
    float c0 = cstate[(size_t)b * HID + 2 * lane];
    float c1 = cstate[(size_t)b * HID + 2 * lane + 1];
    unsigned hpk = *(const unsigned*)&hstate[(size_t)b * HID + 2 * lane];
    float hL0 = 0.f, hL1 = 0.f;

    // activation cols for this lane (gate wid): ca0 = kg*32+l15, ca1 = ca0+16
    const int ca0 = kg * 32 + l15;
    // Z prefetch (one step ahead)
    unsigned short z0, z1;
    {
        const unsigned short* zb = Z + (size_t)b * GC + wid * HID;
        z0 = zb[ca0]; z1 = zb[ca0 + 16];
    }
    const int bpbase = kg * 16;             // bpermute byte-addr base

    for (int t = 0; t < chunk; ++t) {
        // ---- A-frags from lane-local h pairs (wave-internal, no barrier) ----
        short8v ah[4];
        #pragma unroll
        for (int ks = 0; ks < 4; ++ks) {
            int a0 = __builtin_amdgcn_ds_bpermute(bpbase + ks * 64 + 0,  (int)hpk);
            int a1 = __builtin_amdgcn_ds_bpermute(bpbase + ks * 64 + 4,  (int)hpk);
            int a2 = __builtin_amdgcn_ds_bpermute(bpbase + ks * 64 + 8,  (int)hpk);
            int a3 = __builtin_amdgcn_ds_bpermute(bpbase + ks * 64 + 12, (int)hpk);
            union { int i[4]; short8v s; } u;
            u.i[0] = a0; u.i[1] = a1; u.i[2] = a2; u.i[3] = a3;
            ah[ks] = u.s;
        }

        float4v acc[8];
        #pragma unroll
        for (int n = 0; n < 8; ++n)
            #pragma unroll
            for (int j = 0; j < 4; ++j) acc[n][j] = 0.f;

        __builtin_amdgcn_s_setprio(1);
        #pragma unroll
        for (int ks = 0; ks < 4; ++ks)
            #pragma unroll
            for (int n = 0; n < 8; ++n)
                acc[n] = __builtin_amdgcn_mfma_f32_16x16x32_bf16(ah[ks], bw[n][ks], acc[n], 0, 0, 0);
        __builtin_amdgcn_s_setprio(0);

        // ---- in-wave activation of this lane's 2 cols (n = 2kg, 2kg+1) ----
        // static-index selects keep acc in registers (rule #20)
        float s0 = (kg == 0) ? acc[0][0] : (kg == 1) ? acc[2][0]
                 : (kg == 2) ? acc[4][0] : acc[6][0];
        float s1 = (kg == 0) ? acc[1][0] : (kg == 1) ? acc[3][0]
                 : (kg == 2) ? acc[5][0] : acc[7][0];
        s0 += bf2f(z0);
        s1 += bf2f(z1);

        {   // prefetch Z[t+1] (flies across the barrier; consumed next step)
            const int tn = (t + 1 < chunk) ? (t + 1) : t;
            const unsigned short* zb = Z + ((size_t)tn * BATCH + b) * GC + wid * HID;
            z0 = zb[ca0]; z1 = zb[ca0 + 16];
        }

        float v0, v1;
        if (wid == 0)      { v0 = fast_cos(s0);               v1 = fast_cos(s1); }
        else if (wid == 1) { v0 = (fast_cos(s0) + 1.f) * .5f; v1 = (fast_cos(s1) + 1.f) * .5f; }
        else if (wid == 2) { v0 = fast_tanh(s0);              v1 = fast_tanh(s1); }
        else               { v0 = fast_sigmoid(s0);           v1 = fast_sigmoid(s1); }

        const int par = t & 1;
        gact[par][wid][ca0]      = v0;
        gact[par][wid][ca0 + 16] = v1;

        BAR();  // the ONLY barrier: gact ready; prior reads drained

        // ---- cell update (all waves redundant, identical f32 math) ----
        float2v fc = *(const float2v*)&gact[par][0][2 * lane];
        float2v iv = *(const float2v*)&gact[par][1][2 * lane];
        float2v gv = *(const float2v*)&gact[par][2][2 * lane];
        float2v ov = *(const float2v*)&gact[par][3][2 * lane];

        const float pair = fc[0] * fc[1];
        float R = pair;
        R *= dpp1<0x111, 0xf>(R);       // row_shr:1
        R *= dpp1<0x112, 0xf>(R);       // row_shr:2
        R *= dpp1<0x114, 0xf>(R);       // row_shr:4
        R *= dpp1<0x118, 0xf>(R);       // row_shr:8  (16-lane incl scan)
        const float Erow = dpp1<0x111, 0xf>(R);
        const float T0 = __shfl(R, 15);
        const float T1 = __shfl(R, 31);
        const float T2 = __shfl(R, 47);
        const float rp = (kg == 0) ? 1.f : (kg == 1) ? T0
                       : (kg == 2) ? T0 * T1 : T0 * T1 * T2;
        const float E  = Erow * rp;                          // excl prefix
        const float f0 = (E * fc[0] + 1.f) * 0.5f;
        const float f1 = (E * pair  + 1.f) * 0.5f;

        const float cn0 = fmaf(f0, c0, iv[0] * gv[0]);
        const float cn1 = fmaf(f1, c1, iv[1] * gv[1]);
        const float hn0 = ov[0] * fast_tanh(cn0);
        const float hn1 = ov[1] * fast_tanh(cn1);
        c0 = cn0; c1 = cn1; hL0 = hn0; hL1 = hn1;
        hpk = (unsigned)f2bf(hn0) | ((unsigned)f2bf(hn1) << 16);

        if (wid == 0) {
            float2v o2; o2[0] = hn0; o2[1] = hn1;
            *(float2v*)&out[((size_t)(t0 + t) * BATCH + b) * HID + 2 * lane] = o2;
        }
        // no second barrier: next-step A-frags come from lane-local hpk via
        // bpermute; gact parity buffer + BAR's lgkm drain prevent WAR races.
    }

    // save state; final hx/cx tails
    if (wid == 0) {
        hstate[(size_t)b * HID + 2 * lane]     = f2bf(hL0);
        hstate[(size_t)b * HID + 2 * lane + 1] = f2bf(hL1);
        cstate[(size_t)b * HID + 2 * lane]     = c0;
        cstate[(size_t)b * HID + 2 * lane + 1] = c1;
        if (last) {
            const size_t base = (size_t)SEQ * BATCH * HID;
            const size_t ro = (size_t)b * HID + 2 * lane;
            float2v h2, c2;
            h2[0] = hL0; h2[1] = hL1; c2[0] = c0; c2[1] = c1;
            *(float2v*)&out[base + ro] = h2;
            *(float2v*)&out[base + (size_t)BATCH * HID + ro] = c2;
        }
    }
}

// ---------------------------------------------------------------------------
extern "C" void kernel_launch(void* const* d_in, const int* in_sizes, int n_in,
                              void* d_out, int out_size, void* d_ws, size_t ws_size,
                              hipStream_t stream) {
    const float* X  = (const float*)d_in[0];
    const float* Wf = (const float*)d_in[1];
    const float* bf = (const float*)d_in[2];
    const float* Wi = (const float*)d_in[3];
    const float* bi = (const float*)d_in[4];
    const float* Wg = (const float*)d_in[5];
    const float* bg = (const float*)d_in[6];
    const float* Wo = (const float*)d_in[7];
    const float* bo = (const float*)d_in[8];
    float* out = (float*)d_out;

    char* ws = (char*)d_ws;
    unsigned short* hstate = (unsigned short*)ws;                 // 128 KB used
    float*          cstate = (float*)(ws + 256 * 1024);           // 256 KB
    char*           dynws  = ws + 1024 * 1024;

    const size_t xstep = (size_t)BATCH * HID * sizeof(unsigned short);  // 128 KB
    const size_t zstep = (size_t)BATCH * GC  * sizeof(unsigned short);  // 512 KB
    size_t cap = (ws_size > (1u << 20)) ? ws_size - (1u << 20) : 0;
    int Tc = (int)(cap / (xstep + zstep));
    if (Tc > SEQ) Tc = SEQ;
    if (Tc < 1)   Tc = 1;

    hipMemsetAsync(ws, 0, 1024 * 1024, stream);   // zero h/c state

    for (int t0 = 0; t0 < SEQ; t0 += Tc) {
        const int chunk = (SEQ - t0 < Tc) ? (SEQ - t0) : Tc;
        unsigned short* Xbf  = (unsigned short*)dynws;
        unsigned short* Zbuf = (unsigned short*)(dynws + (size_t)chunk * xstep);

        const int n8 = chunk * BATCH * HID / 8;
        xbf_kernel<<<2048, 256, 0, stream>>>(
            X + (size_t)t0 * BATCH * HID, Xbf, n8);
        qlstm_xgemm<<<chunk * BATCH / 128, 512, 0, stream>>>(
            Xbf, Wf, bf, Wi, bi, Wg, bg, Wo, bo, Zbuf);
        qlstm_rec<<<BATCH, 256, 0, stream>>>(
            Zbuf, Wf, Wi, Wg, Wo, out, hstate, cstate,
            t0, chunk, (t0 + chunk == SEQ) ? 1 : 0);
    }
}

// Round 8
// 1519.695 us; speedup vs baseline: 1.0822x; 1.0822x over previous
//
#include <hip/hip_runtime.h>

#define SEQ   1024
#define BATCH 512
#define HID   128
#define GC    512   // 4 gates * HID

typedef __attribute__((ext_vector_type(8))) short          short8v;
typedef __attribute__((ext_vector_type(4))) float          float4v;
typedef __attribute__((ext_vector_type(2))) float          float2v;
typedef __attribute__((ext_vector_type(4))) unsigned short ushort4v;
typedef __attribute__((ext_vector_type(8))) unsigned short ushort8v;

__device__ __forceinline__ unsigned short f2bf(float f) {
    union { float f; unsigned u; } v; v.f = f;
    return (unsigned short)((v.u + 0x7fffu + ((v.u >> 16) & 1u)) >> 16);
}
__device__ __forceinline__ float bf2f(unsigned short u) {
    union { unsigned u; float f; } v; v.u = ((unsigned)u) << 16;
    return v.f;
}
__device__ __forceinline__ float fast_cos(float x) {
    return __builtin_amdgcn_cosf(x * 0.15915494309189535f);   // v_cos takes revolutions
}
__device__ __forceinline__ float fast_sigmoid(float x) {
    return __builtin_amdgcn_rcpf(1.0f + __builtin_amdgcn_exp2f(-1.4426950408889634f * x));
}
__device__ __forceinline__ float fast_tanh(float x) {
    return 1.0f - 2.0f * __builtin_amdgcn_rcpf(1.0f + __builtin_amdgcn_exp2f(2.8853900817779268f * x));
}

// DPP helper: returns src shifted by CTRL, invalid/masked lanes get 1.0f
template<int CTRL, int RM>
__device__ __forceinline__ float dpp1(float v) {
    union { float f; int i; } s, o, r;
    s.f = v; o.f = 1.0f;
    r.i = __builtin_amdgcn_update_dpp(o.i, s.i, CTRL, RM, 0xf, false);
    return r.f;
}

// raw barrier: drains LDS only; global loads/stores stay in flight across it
#define BAR() do { asm volatile("s_waitcnt lgkmcnt(0)" ::: "memory");  \
                   __builtin_amdgcn_s_barrier();                       \
                   __builtin_amdgcn_sched_barrier(0); } while (0)

// ---------------------------------------------------------------------------
// Kernel 0: X f32 -> bf16 streaming convert (chunk slice)
// ---------------------------------------------------------------------------
__global__ __launch_bounds__(256) void xbf_kernel(
    const float* __restrict__ X, unsigned short* __restrict__ Xb, int n8)
{
    int i = blockIdx.x * 256 + threadIdx.x;
    const int stride = gridDim.x * 256;
    for (; i < n8; i += stride) {
        float4v a = *(const float4v*)(X + (size_t)i * 8);
        float4v b = *(const float4v*)(X + (size_t)i * 8 + 4);
        ushort8v o;
        #pragma unroll
        for (int j = 0; j < 4; ++j) { o[j] = f2bf(a[j]); o[4 + j] = f2bf(b[j]); }
        *(ushort8v*)(Xb + (size_t)i * 8) = o;
    }
}

// ---------------------------------------------------------------------------
// Kernel 1: Z[row][g*128+c] = bf16( Xb[row][:] @ Wg_x[:,c] + b ).  (unchanged)
// ---------------------------------------------------------------------------
__global__ __launch_bounds__(512, 4) void qlstm_xgemm(
    const unsigned short* __restrict__ Xb,   // [rows][128] bf16
    const float* __restrict__ Wf, const float* __restrict__ bfp,
    const float* __restrict__ Wi, const float* __restrict__ bip,
    const float* __restrict__ Wg, const float* __restrict__ bgp,
    const float* __restrict__ Wo, const float* __restrict__ bop,
    unsigned short* __restrict__ Z)
{
    const int tid = threadIdx.x, lane = tid & 63, wid = tid >> 6;
    const int l15 = lane & 15, kg = lane >> 4;
    const int g = wid >> 1;
    const float* Wsel = (g == 0) ? Wf : (g == 1) ? Wi : (g == 2) ? Wg : Wo;
    const float* bsel = (g == 0) ? bfp : (g == 1) ? bip : (g == 2) ? bgp : bop;
    const int cb  = (wid & 1) * 64;
    const int zcb = wid * 64;

    short8v aw[4][4];
    #pragma unroll
    for (int mt = 0; mt < 4; ++mt) {
        const int col = cb + mt * 16 + l15;
        #pragma unroll
        for (int ks = 0; ks < 4; ++ks) {
            const int k0 = ks * 32 + kg * 8;
            short8v a;
            #pragma unroll
            for (int j = 0; j < 8; ++j)
                a[j] = (short)f2bf(Wsel[(size_t)(k0 + j) * HID + col]);
            aw[mt][ks] = a;
        }
    }
    ushort4v biasb[4];
    #pragma unroll
    for (int mt = 0; mt < 4; ++mt)
        #pragma unroll
        for (int j = 0; j < 4; ++j)
            biasb[mt][j] = f2bf(bsel[cb + mt * 16 + kg * 4 + j]);

    const int rowbase = blockIdx.x * 128;

    short8v bx[4];
    {
        const unsigned short* xr = Xb + (size_t)(rowbase + l15) * HID;
        #pragma unroll
        for (int ks = 0; ks < 4; ++ks)
            bx[ks] = *(const short8v*)(xr + ks * 32 + kg * 8);
    }

    for (int rg = 0; rg < 8; ++rg) {
        float4v acc[4];
        #pragma unroll
        for (int mt = 0; mt < 4; ++mt)
            #pragma unroll
            for (int j = 0; j < 4; ++j) acc[mt][j] = bf2f(biasb[mt][j]);

        #pragma unroll
        for (int ks = 0; ks < 4; ++ks)
            #pragma unroll
            for (int mt = 0; mt < 4; ++mt)
                acc[mt] = __builtin_amdgcn_mfma_f32_16x16x32_bf16(aw[mt][ks], bx[ks], acc[mt], 0, 0, 0);

        if (rg < 7) {
            const unsigned short* xr = Xb + (size_t)(rowbase + (rg + 1) * 16 + l15) * HID;
            #pragma unroll
            for (int ks = 0; ks < 4; ++ks)
                bx[ks] = *(const short8v*)(xr + ks * 32 + kg * 8);
        }

        const size_t zr = (size_t)(rowbase + rg * 16 + l15) * GC + zcb;
        #pragma unroll
        for (int mt = 0; mt < 4; ++mt) {
            ushort4v o;
            #pragma unroll
            for (int j = 0; j < 4; ++j) o[j] = f2bf(acc[mt][j]);
            *(ushort4v*)&Z[zr + mt * 16 + kg * 4] = o;
        }
    }
}

// ---------------------------------------------------------------------------
// Kernel 2: recurrent. 512 WGs x 256 thr (4 waves), 1 batch row/WG, 2 WGs/CU.
// R6 structure + R7's in-wave activation (the only part of R7 that helped):
//   Phase A: wave g computes gate g's h@Wh (A = h broadcast from LDS h_bf,
//     B = Wh frags in regs), then ACTIVATES its own gate in-register (2 cols
//     per lane via static selects; f-gate publishes cos) -> gact[4][128].
//   BAR S1.
//   Phase B: single worker wave (wid == blockIdx&3): 4 b64 gact reads,
//     DPP pair-product cumprod scan, cell update, 2 tanh, h_bf b32 write,
//     out b64 write. BAR S2.
// No bpermute, no redundant work. 2 barriers, proven race-free (R6).
// ---------------------------------------------------------------------------
__global__ __launch_bounds__(256, 2) void qlstm_rec(
    const unsigned short* __restrict__ Z,   // [chunk][BATCH][GC] bf16
    const float* __restrict__ Wf, const float* __restrict__ Wi,
    const float* __restrict__ Wg, const float* __restrict__ Wo,
    float* __restrict__ out,
    unsigned short* __restrict__ hstate,    // bf16 [BATCH][HID]
    float* __restrict__ cstate,             // f32  [BATCH][HID]
    int t0, int chunk, int last)
{
    __shared__ float gact[4][HID];          // activated gates; gate0 = cos(f-pre)
    __shared__ alignas(16) unsigned short h_bf[HID];

    const int tid = threadIdx.x, lane = tid & 63, wid = tid >> 6;
    const int l15 = lane & 15, kg = lane >> 4;
    const int b = blockIdx.x;               // batch row
    const float* Wsel = (wid == 0) ? Wf : (wid == 1) ? Wi : (wid == 2) ? Wg : Wo;
    const bool worker = (wid == (blockIdx.x & 3));   // stagger SIMDs across WGs

    // B-frags: bw[n][ks] = W[128 + ks*32 + kg*8 + j][n*16 + l15]   (128 VGPR)
    short8v bw[8][4];
    #pragma unroll
    for (int n = 0; n < 8; ++n) {
        const int col = n * 16 + l15;
        #pragma unroll
        for (int ks = 0; ks < 4; ++ks) {
            const int k0 = 128 + ks * 32 + kg * 8;
            short8v a;
            #pragma unroll
            for (int j = 0; j < 8; ++j)
                a[j] = (short)f2bf(Wsel[(size_t)(k0 + j) * HID + col]);
            bw[n][ks] = a;
        }
    }

    if (tid < 64)
        ((unsigned*)h_bf)[tid] = ((const unsigned*)(hstate + (size_t)b * HID))[tid];

    // worker-only cell state, cols {2*lane, 2*lane+1}
    float c0 = 0.f, c1 = 0.f, hL0 = 0.f, hL1 = 0.f;
    if (worker) {
        float2v cc = *(const float2v*)&cstate[(size_t)b * HID + 2 * lane];
        c0 = cc[0]; c1 = cc[1];
    }

    // this lane's activation cols (gate wid): ca0 = kg*32+l15, ca1 = ca0+16
    const int ca0 = kg * 32 + l15;
    unsigned short z0, z1;
    {
        const unsigned short* zb = Z + (size_t)b * GC + wid * HID;
        z0 = zb[ca0]; z1 = zb[ca0 + 16];
    }

    BAR();

    for (int t = 0; t < chunk; ++t) {
        // ---- Phase A: h @ Wh (gate = wid), A = h broadcast ----
        short8v ah[4];
        #pragma unroll
        for (int ks = 0; ks < 4; ++ks)
            ah[ks] = *(const short8v*)&h_bf[ks * 32 + kg * 8];

        float4v acc[8];
        #pragma unroll
        for (int n = 0; n < 8; ++n)
            #pragma unroll
            for (int j = 0; j < 4; ++j) acc[n][j] = 0.f;

        __builtin_amdgcn_s_setprio(1);
        #pragma unroll
        for (int ks = 0; ks < 4; ++ks)
            #pragma unroll
            for (int n = 0; n < 8; ++n)
                acc[n] = __builtin_amdgcn_mfma_f32_16x16x32_bf16(ah[ks], bw[n][ks], acc[n], 0, 0, 0);
        __builtin_amdgcn_s_setprio(0);

        // ---- extract this lane's 2 cols (tiles 2kg, 2kg+1; broadcast rows) ----
        float s0 = (kg == 0) ? acc[0][0] : (kg == 1) ? acc[2][0]
                 : (kg == 2) ? acc[4][0] : acc[6][0];
        float s1 = (kg == 0) ? acc[1][0] : (kg == 1) ? acc[3][0]
                 : (kg == 2) ? acc[5][0] : acc[7][0];
        s0 += bf2f(z0);
        s1 += bf2f(z1);

        {   // prefetch Z[t+1] (flies across both barriers)
            const int tn = (t + 1 < chunk) ? (t + 1) : t;
            const unsigned short* zb = Z + ((size_t)tn * BATCH + b) * GC + wid * HID;
            z0 = zb[ca0]; z1 = zb[ca0 + 16];
        }

        // ---- in-wave activation of own gate ----
        float v0, v1;
        if (wid == 0)      { v0 = fast_cos(s0);               v1 = fast_cos(s1); }
        else if (wid == 1) { v0 = (fast_cos(s0) + 1.f) * .5f; v1 = (fast_cos(s1) + 1.f) * .5f; }
        else if (wid == 2) { v0 = fast_tanh(s0);              v1 = fast_tanh(s1); }
        else               { v0 = fast_sigmoid(s0);           v1 = fast_sigmoid(s1); }
        gact[wid][ca0]      = v0;
        gact[wid][ca0 + 16] = v1;

        BAR();  // S1: gact ready

        // ---- Phase B: worker wave only; cols {2*lane, 2*lane+1} ----
        if (worker) {
            float2v fc = *(const float2v*)&gact[0][2 * lane];
            float2v iv = *(const float2v*)&gact[1][2 * lane];
            float2v gv = *(const float2v*)&gact[2][2 * lane];
            float2v ov = *(const float2v*)&gact[3][2 * lane];

            const float pair = fc[0] * fc[1];
            float R = pair;
            R *= dpp1<0x111, 0xf>(R);       // row_shr:1
            R *= dpp1<0x112, 0xf>(R);       // row_shr:2
            R *= dpp1<0x114, 0xf>(R);       // row_shr:4
            R *= dpp1<0x118, 0xf>(R);       // row_shr:8  (16-lane incl scan)
            const float Erow = dpp1<0x111, 0xf>(R);
            const float T0 = __shfl(R, 15);
            const float T1 = __shfl(R, 31);
            const float T2 = __shfl(R, 47);
            const float rp = (kg == 0) ? 1.f : (kg == 1) ? T0
                           : (kg == 2) ? T0 * T1 : T0 * T1 * T2;
            const float E  = Erow * rp;                      // exclusive prefix
            const float f0 = (E * fc[0] + 1.f) * 0.5f;
            const float f1 = (E * pair  + 1.f) * 0.5f;

            const float cn0 = fmaf(f0, c0, iv[0] * gv[0]);
            const float cn1 = fmaf(f1, c1, iv[1] * gv[1]);
            const float hn0 = ov[0] * fast_tanh(cn0);
            const float hn1 = ov[1] * fast_tanh(cn1);
            c0 = cn0; c1 = cn1; hL0 = hn0; hL1 = hn1;

            *(unsigned*)&h_bf[2 * lane] =
                (unsigned)f2bf(hn0) | ((unsigned)f2bf(hn1) << 16);
            float2v o2; o2[0] = hn0; o2[1] = hn1;
            *(float2v*)&out[((size_t)(t0 + t) * BATCH + b) * HID + 2 * lane] = o2;
        }
        BAR();  // S2: h_bf ready for next step
    }

    // save state; final hx/cx tails (worker holds them)
    if (worker) {
        hstate[(size_t)b * HID + 2 * lane]     = f2bf(hL0);
        hstate[(size_t)b * HID + 2 * lane + 1] = f2bf(hL1);
        float2v c2s; c2s[0] = c0; c2s[1] = c1;
        *(float2v*)&cstate[(size_t)b * HID + 2 * lane] = c2s;
        if (last) {
            const size_t base = (size_t)SEQ * BATCH * HID;
            const size_t ro = (size_t)b * HID + 2 * lane;
            float2v h2, c2;
            h2[0] = hL0; h2[1] = hL1; c2[0] = c0; c2[1] = c1;
            *(float2v*)&out[base + ro] = h2;
            *(float2v*)&out[base + (size_t)BATCH * HID + ro] = c2;
        }
    }
}

// ---------------------------------------------------------------------------
extern "C" void kernel_launch(void* const* d_in, const int* in_sizes, int n_in,
                              void* d_out, int out_size, void* d_ws, size_t ws_size,
                              hipStream_t stream) {
    const float* X  = (const float*)d_in[0];
    const float* Wf = (const float*)d_in[1];
    const float* bf = (const float*)d_in[2];
    const float* Wi = (const float*)d_in[3];
    const float* bi = (const float*)d_in[4];
    const float* Wg = (const float*)d_in[5];
    const float* bg = (const float*)d_in[6];
    const float* Wo = (const float*)d_in[7];
    const float* bo = (const float*)d_in[8];
    float* out = (float*)d_out;

    char* ws = (char*)d_ws;
    unsigned short* hstate = (unsigned short*)ws;                 // 128 KB used
    float*          cstate = (float*)(ws + 256 * 1024);           // 256 KB
    char*           dynws  = ws + 1024 * 1024;

    const size_t xstep = (size_t)BATCH * HID * sizeof(unsigned short);  // 128 KB
    const size_t zstep = (size_t)BATCH * GC  * sizeof(unsigned short);  // 512 KB
    size_t cap = (ws_size > (1u << 20)) ? ws_size - (1u << 20) : 0;
    int Tc = (int)(cap / (xstep + zstep));
    if (Tc > SEQ) Tc = SEQ;
    if (Tc < 1)   Tc = 1;

    hipMemsetAsync(ws, 0, 1024 * 1024, stream);   // zero h/c state

    for (int t0 = 0; t0 < SEQ; t0 += Tc) {
        const int chunk = (SEQ - t0 < Tc) ? (SEQ - t0) : Tc;
        unsigned short* Xbf  = (unsigned short*)dynws;
        unsigned short* Zbuf = (unsigned short*)(dynws + (size_t)chunk * xstep);

        const int n8 = chunk * BATCH * HID / 8;
        xbf_kernel<<<2048, 256, 0, stream>>>(
            X + (size_t)t0 * BATCH * HID, Xbf, n8);
        qlstm_xgemm<<<chunk * BATCH / 128, 512, 0, stream>>>(
            Xbf, Wf, bf, Wi, bi, Wg, bg, Wo, bo, Zbuf);
        qlstm_rec<<<BATCH, 256, 0, stream>>>(
            Zbuf, Wf, Wi, Wg, Wo, out, hstate, cstate,
            t0, chunk, (t0 + chunk == SEQ) ? 1 : 0);
    }
}

// Round 9
// 1420.080 us; speedup vs baseline: 1.1581x; 1.0701x over previous
//
#include <hip/hip_runtime.h>

#define SEQ   1024
#define BATCH 512
#define HID   128
#define GC    512   // 4 gates * HID

typedef __attribute__((ext_vector_type(8))) short          short8v;
typedef __attribute__((ext_vector_type(4))) float          float4v;
typedef __attribute__((ext_vector_type(2))) float          float2v;
typedef __attribute__((ext_vector_type(4))) unsigned short ushort4v;
typedef __attribute__((ext_vector_type(8))) unsigned short ushort8v;

__device__ __forceinline__ unsigned short f2bf(float f) {
    union { float f; unsigned u; } v; v.f = f;
    return (unsigned short)((v.u + 0x7fffu + ((v.u >> 16) & 1u)) >> 16);
}
__device__ __forceinline__ float bf2f(unsigned short u) {
    union { unsigned u; float f; } v; v.u = ((unsigned)u) << 16;
    return v.f;
}
__device__ __forceinline__ float fast_cos(float x) {
    return __builtin_amdgcn_cosf(x * 0.15915494309189535f);   // v_cos takes revolutions
}
__device__ __forceinline__ float fast_sigmoid(float x) {
    return __builtin_amdgcn_rcpf(1.0f + __builtin_amdgcn_exp2f(-1.4426950408889634f * x));
}
__device__ __forceinline__ float fast_tanh(float x) {
    return 1.0f - 2.0f * __builtin_amdgcn_rcpf(1.0f + __builtin_amdgcn_exp2f(2.8853900817779268f * x));
}

// DPP helper: returns src shifted by CTRL, invalid/masked lanes get 1.0f
template<int CTRL, int RM>
__device__ __forceinline__ float dpp1(float v) {
    union { float f; int i; } s, o, r;
    s.f = v; o.f = 1.0f;
    r.i = __builtin_amdgcn_update_dpp(o.i, s.i, CTRL, RM, 0xf, false);
    return r.f;
}

// raw barrier: drains LDS only; global loads/stores stay in flight across it
#define BAR() do { asm volatile("s_waitcnt lgkmcnt(0)" ::: "memory");  \
                   __builtin_amdgcn_s_barrier();                       \
                   __builtin_amdgcn_sched_barrier(0); } while (0)

// ---------------------------------------------------------------------------
// Kernel 0: X f32 -> bf16 streaming convert (chunk slice)
// ---------------------------------------------------------------------------
__global__ __launch_bounds__(256) void xbf_kernel(
    const float* __restrict__ X, unsigned short* __restrict__ Xb, int n8)
{
    int i = blockIdx.x * 256 + threadIdx.x;
    const int stride = gridDim.x * 256;
    for (; i < n8; i += stride) {
        float4v a = *(const float4v*)(X + (size_t)i * 8);
        float4v b = *(const float4v*)(X + (size_t)i * 8 + 4);
        ushort8v o;
        #pragma unroll
        for (int j = 0; j < 4; ++j) { o[j] = f2bf(a[j]); o[4 + j] = f2bf(b[j]); }
        *(ushort8v*)(Xb + (size_t)i * 8) = o;
    }
}

// ---------------------------------------------------------------------------
// Kernel 1: Z[row][g*128+c] = bf16( Xb[row][:] @ Wg_x[:,c] + b ).  (unchanged)
// ---------------------------------------------------------------------------
__global__ __launch_bounds__(512, 4) void qlstm_xgemm(
    const unsigned short* __restrict__ Xb,   // [rows][128] bf16
    const float* __restrict__ Wf, const float* __restrict__ bfp,
    const float* __restrict__ Wi, const float* __restrict__ bip,
    const float* __restrict__ Wg, const float* __restrict__ bgp,
    const float* __restrict__ Wo, const float* __restrict__ bop,
    unsigned short* __restrict__ Z)
{
    const int tid = threadIdx.x, lane = tid & 63, wid = tid >> 6;
    const int l15 = lane & 15, kg = lane >> 4;
    const int g = wid >> 1;
    const float* Wsel = (g == 0) ? Wf : (g == 1) ? Wi : (g == 2) ? Wg : Wo;
    const float* bsel = (g == 0) ? bfp : (g == 1) ? bip : (g == 2) ? bgp : bop;
    const int cb  = (wid & 1) * 64;
    const int zcb = wid * 64;

    short8v aw[4][4];
    #pragma unroll
    for (int mt = 0; mt < 4; ++mt) {
        const int col = cb + mt * 16 + l15;
        #pragma unroll
        for (int ks = 0; ks < 4; ++ks) {
            const int k0 = ks * 32 + kg * 8;
            short8v a;
            #pragma unroll
            for (int j = 0; j < 8; ++j)
                a[j] = (short)f2bf(Wsel[(size_t)(k0 + j) * HID + col]);
            aw[mt][ks] = a;
        }
    }
    ushort4v biasb[4];
    #pragma unroll
    for (int mt = 0; mt < 4; ++mt)
        #pragma unroll
        for (int j = 0; j < 4; ++j)
            biasb[mt][j] = f2bf(bsel[cb + mt * 16 + kg * 4 + j]);

    const int rowbase = blockIdx.x * 128;

    short8v bx[4];
    {
        const unsigned short* xr = Xb + (size_t)(rowbase + l15) * HID;
        #pragma unroll
        for (int ks = 0; ks < 4; ++ks)
            bx[ks] = *(const short8v*)(xr + ks * 32 + kg * 8);
    }

    for (int rg = 0; rg < 8; ++rg) {
        float4v acc[4];
        #pragma unroll
        for (int mt = 0; mt < 4; ++mt)
            #pragma unroll
            for (int j = 0; j < 4; ++j) acc[mt][j] = bf2f(biasb[mt][j]);

        #pragma unroll
        for (int ks = 0; ks < 4; ++ks)
            #pragma unroll
            for (int mt = 0; mt < 4; ++mt)
                acc[mt] = __builtin_amdgcn_mfma_f32_16x16x32_bf16(aw[mt][ks], bx[ks], acc[mt], 0, 0, 0);

        if (rg < 7) {
            const unsigned short* xr = Xb + (size_t)(rowbase + (rg + 1) * 16 + l15) * HID;
            #pragma unroll
            for (int ks = 0; ks < 4; ++ks)
                bx[ks] = *(const short8v*)(xr + ks * 32 + kg * 8);
        }

        const size_t zr = (size_t)(rowbase + rg * 16 + l15) * GC + zcb;
        #pragma unroll
        for (int mt = 0; mt < 4; ++mt) {
            ushort4v o;
            #pragma unroll
            for (int j = 0; j < 4; ++j) o[j] = f2bf(acc[mt][j]);
            *(ushort4v*)&Z[zr + mt * 16 + kg * 4] = o;
        }
    }
}

// ---------------------------------------------------------------------------
// Kernel 2: recurrent. 256 WGs x 256 thr (4 waves), TWO batch rows per WG
// packed in the MFMA M-slots (A[m][k] = h_{m&1}[k], replicated), 1 WG/CU.
// D[m=kg*4+r][n=l15] => reg parity r&1 = batch row: every lane holds both
// rows' preacts for its 2 cols. Phase A: wave g = gate g, 32 MFMA serving
// 2 rows (pipe demand halved vs R8). Act: 4 trans/lane (2 cols x 2 rows),
// publish gact[row][gate][col]. BAR S1. Workers: 2 waves (one per row,
// staggered across SIMDs by blockIdx), R8's DPP scan + cell per row.
// BAR S2.
// ---------------------------------------------------------------------------
__global__ __launch_bounds__(256, 1) void qlstm_rec(
    const unsigned short* __restrict__ Z,   // [chunk][BATCH][GC] bf16
    const float* __restrict__ Wf, const float* __restrict__ Wi,
    const float* __restrict__ Wg, const float* __restrict__ Wo,
    float* __restrict__ out,
    unsigned short* __restrict__ hstate,    // bf16 [BATCH][HID]
    float* __restrict__ cstate,             // f32  [BATCH][HID]
    int t0, int chunk, int last)
{
    __shared__ float gact[2][4][HID];       // [row][gate][col]; gate0 = cos(f)
    __shared__ alignas(16) unsigned short h_bf[2][HID];

    const int tid = threadIdx.x, lane = tid & 63, wid = tid >> 6;
    const int l15 = lane & 15, kg = lane >> 4;
    const int b0 = blockIdx.x * 2;          // batch rows b0, b0+1
    const float* Wsel = (wid == 0) ? Wf : (wid == 1) ? Wi : (wid == 2) ? Wg : Wo;
    // worker pair staggered across SIMDs: waves {0,1} or {2,3}
    const int  wrow   = wid & 1;
    const bool worker = ((wid >> 1) == (blockIdx.x & 1));

    // B-frags: bw[n][ks] = W[128 + ks*32 + kg*8 + j][n*16 + l15]   (128 VGPR)
    short8v bw[8][4];
    #pragma unroll
    for (int n = 0; n < 8; ++n) {
        const int col = n * 16 + l15;
        #pragma unroll
        for (int ks = 0; ks < 4; ++ks) {
            const int k0 = 128 + ks * 32 + kg * 8;
            short8v a;
            #pragma unroll
            for (int j = 0; j < 8; ++j)
                a[j] = (short)f2bf(Wsel[(size_t)(k0 + j) * HID + col]);
            bw[n][ks] = a;
        }
    }

    // h_bf init: rows b0, b0+1 contiguous in hstate (256 ushorts = 128 dwords)
    if (tid < 128)
        ((unsigned*)h_bf)[tid] = ((const unsigned*)(hstate + (size_t)b0 * HID))[tid];

    // worker-only cell state, its row's cols {2*lane, 2*lane+1}
    float c0 = 0.f, c1 = 0.f, hL0 = 0.f, hL1 = 0.f;
    if (worker) {
        float2v cc = *(const float2v*)&cstate[(size_t)(b0 + wrow) * HID + 2 * lane];
        c0 = cc[0]; c1 = cc[1];
    }

    // this lane's activation cols (gate wid): ca0 = kg*32+l15, ca1 = ca0+16
    const int ca0 = kg * 32 + l15;
    unsigned short z00, z01, z10, z11;      // z[row][colpair]
    {
        const unsigned short* zb = Z + (size_t)b0 * GC + wid * HID;
        z00 = zb[ca0]; z01 = zb[ca0 + 16];
        z10 = zb[GC + ca0]; z11 = zb[GC + ca0 + 16];
    }

    BAR();

    for (int t = 0; t < chunk; ++t) {
        // ---- Phase A: [2 rows] @ Wh (gate = wid), rows replicated in M ----
        short8v ah[4];                      // A[m=l15][k] = h_{l15&1}[k]
        #pragma unroll
        for (int ks = 0; ks < 4; ++ks)
            ah[ks] = *(const short8v*)&h_bf[l15 & 1][ks * 32 + kg * 8];

        float4v acc[8];
        #pragma unroll
        for (int n = 0; n < 8; ++n)
            #pragma unroll
            for (int j = 0; j < 4; ++j) acc[n][j] = 0.f;

        __builtin_amdgcn_s_setprio(1);
        #pragma unroll
        for (int ks = 0; ks < 4; ++ks)
            #pragma unroll
            for (int n = 0; n < 8; ++n)
                acc[n] = __builtin_amdgcn_mfma_f32_16x16x32_bf16(ah[ks], bw[n][ks], acc[n], 0, 0, 0);
        __builtin_amdgcn_s_setprio(0);

        // ---- extract: tiles n=2kg,2kg+1; reg parity = batch row ----
        float s0r0 = (kg == 0) ? acc[0][0] : (kg == 1) ? acc[2][0]
                   : (kg == 2) ? acc[4][0] : acc[6][0];
        float s0r1 = (kg == 0) ? acc[0][1] : (kg == 1) ? acc[2][1]
                   : (kg == 2) ? acc[4][1] : acc[6][1];
        float s1r0 = (kg == 0) ? acc[1][0] : (kg == 1) ? acc[3][0]
                   : (kg == 2) ? acc[5][0] : acc[7][0];
        float s1r1 = (kg == 0) ? acc[1][1] : (kg == 1) ? acc[3][1]
                   : (kg == 2) ? acc[5][1] : acc[7][1];
        s0r0 += bf2f(z00); s1r0 += bf2f(z01);
        s0r1 += bf2f(z10); s1r1 += bf2f(z11);

        {   // prefetch Z[t+1] (flies across both barriers)
            const int tn = (t + 1 < chunk) ? (t + 1) : t;
            const unsigned short* zb = Z + ((size_t)tn * BATCH + b0) * GC + wid * HID;
            z00 = zb[ca0]; z01 = zb[ca0 + 16];
            z10 = zb[GC + ca0]; z11 = zb[GC + ca0 + 16];
        }

        // ---- in-wave activation of own gate, both rows ----
        float v00, v01, v10, v11;
        if (wid == 0) {
            v00 = fast_cos(s0r0); v01 = fast_cos(s1r0);
            v10 = fast_cos(s0r1); v11 = fast_cos(s1r1);
        } else if (wid == 1) {
            v00 = (fast_cos(s0r0) + 1.f) * .5f; v01 = (fast_cos(s1r0) + 1.f) * .5f;
            v10 = (fast_cos(s0r1) + 1.f) * .5f; v11 = (fast_cos(s1r1) + 1.f) * .5f;
        } else if (wid == 2) {
            v00 = fast_tanh(s0r0); v01 = fast_tanh(s1r0);
            v10 = fast_tanh(s0r1); v11 = fast_tanh(s1r1);
        } else {
            v00 = fast_sigmoid(s0r0); v01 = fast_sigmoid(s1r0);
            v10 = fast_sigmoid(s0r1); v11 = fast_sigmoid(s1r1);
        }
        gact[0][wid][ca0]      = v00;
        gact[0][wid][ca0 + 16] = v01;
        gact[1][wid][ca0]      = v10;
        gact[1][wid][ca0 + 16] = v11;

        BAR();  // S1: gact ready

        // ---- Phase B: worker waves; row wrow, cols {2*lane, 2*lane+1} ----
        if (worker) {
            float2v fc = *(const float2v*)&gact[wrow][0][2 * lane];
            float2v iv = *(const float2v*)&gact[wrow][1][2 * lane];
            float2v gv = *(const float2v*)&gact[wrow][2][2 * lane];
            float2v ov = *(const float2v*)&gact[wrow][3][2 * lane];

            const float pair = fc[0] * fc[1];
            float R = pair;
            R *= dpp1<0x111, 0xf>(R);       // row_shr:1
            R *= dpp1<0x112, 0xf>(R);       // row_shr:2
            R *= dpp1<0x114, 0xf>(R);       // row_shr:4
            R *= dpp1<0x118, 0xf>(R);       // row_shr:8  (16-lane incl scan)
            const float Erow = dpp1<0x111, 0xf>(R);
            const float T0 = __shfl(R, 15);
            const float T1 = __shfl(R, 31);
            const float T2 = __shfl(R, 47);
            const float rp = (kg == 0) ? 1.f : (kg == 1) ? T0
                           : (kg == 2) ? T0 * T1 : T0 * T1 * T2;
            const float E  = Erow * rp;                      // exclusive prefix
            const float f0 = (E * fc[0] + 1.f) * 0.5f;
            const float f1 = (E * pair  + 1.f) * 0.5f;

            const float cn0 = fmaf(f0, c0, iv[0] * gv[0]);
            const float cn1 = fmaf(f1, c1, iv[1] * gv[1]);
            const float hn0 = ov[0] * fast_tanh(cn0);
            const float hn1 = ov[1] * fast_tanh(cn1);
            c0 = cn0; c1 = cn1; hL0 = hn0; hL1 = hn1;

            *(unsigned*)&h_bf[wrow][2 * lane] =
                (unsigned)f2bf(hn0) | ((unsigned)f2bf(hn1) << 16);
            float2v o2; o2[0] = hn0; o2[1] = hn1;
            *(float2v*)&out[((size_t)(t0 + t) * BATCH + b0 + wrow) * HID + 2 * lane] = o2;
        }
        BAR();  // S2: h_bf ready for next step
    }

    // save state; final hx/cx tails (workers hold them)
    if (worker) {
        const size_t ro = (size_t)(b0 + wrow) * HID + 2 * lane;
        hstate[ro]     = f2bf(hL0);
        hstate[ro + 1] = f2bf(hL1);
        float2v c2s; c2s[0] = c0; c2s[1] = c1;
        *(float2v*)&cstate[ro] = c2s;
        if (last) {
            const size_t base = (size_t)SEQ * BATCH * HID;
            float2v h2, c2;
            h2[0] = hL0; h2[1] = hL1; c2[0] = c0; c2[1] = c1;
            *(float2v*)&out[base + ro] = h2;
            *(float2v*)&out[base + (size_t)BATCH * HID + ro] = c2;
        }
    }
}

// ---------------------------------------------------------------------------
extern "C" void kernel_launch(void* const* d_in, const int* in_sizes, int n_in,
                              void* d_out, int out_size, void* d_ws, size_t ws_size,
                              hipStream_t stream) {
    const float* X  = (const float*)d_in[0];
    const float* Wf = (const float*)d_in[1];
    const float* bf = (const float*)d_in[2];
    const float* Wi = (const float*)d_in[3];
    const float* bi = (const float*)d_in[4];
    const float* Wg = (const float*)d_in[5];
    const float* bg = (const float*)d_in[6];
    const float* Wo = (const float*)d_in[7];
    const float* bo = (const float*)d_in[8];
    float* out = (float*)d_out;

    char* ws = (char*)d_ws;
    unsigned short* hstate = (unsigned short*)ws;                 // 128 KB used
    float*          cstate = (float*)(ws + 256 * 1024);           // 256 KB
    char*           dynws  = ws + 1024 * 1024;

    const size_t xstep = (size_t)BATCH * HID * sizeof(unsigned short);  // 128 KB
    const size_t zstep = (size_t)BATCH * GC  * sizeof(unsigned short);  // 512 KB
    size_t cap = (ws_size > (1u << 20)) ? ws_size - (1u << 20) : 0;
    int Tc = (int)(cap / (xstep + zstep));
    if (Tc > SEQ) Tc = SEQ;
    if (Tc < 1)   Tc = 1;

    hipMemsetAsync(ws, 0, 1024 * 1024, stream);   // zero h/c state

    for (int t0 = 0; t0 < SEQ; t0 += Tc) {
        const int chunk = (SEQ - t0 < Tc) ? (SEQ - t0) : Tc;
        unsigned short* Xbf  = (unsigned short*)dynws;
        unsigned short* Zbuf = (unsigned short*)(dynws + (size_t)chunk * xstep);

        const int n8 = chunk * BATCH * HID / 8;
        xbf_kernel<<<2048, 256, 0, stream>>>(
            X + (size_t)t0 * BATCH * HID, Xbf, n8);
        qlstm_xgemm<<<chunk * BATCH / 128, 512, 0, stream>>>(
            Xbf, Wf, bf, Wi, bi, Wg, bg, Wo, bo, Zbuf);
        qlstm_rec<<<BATCH / 2, 256, 0, stream>>>(
            Zbuf, Wf, Wi, Wg, Wo, out, hstate, cstate,
            t0, chunk, (t0 + chunk == SEQ) ? 1 : 0);
    }
}